// Round 1
// baseline (121.724 us; speedup 1.0000x reference)
//
#include <hip/hip_runtime.h>

#define DIM 16
#define K_TOK 16   // tokens per stream; one 4-lane quad owns a stream

// out[b*DIM + d] = bias[d], vectorized float4 (d_out poisoned pre-launch)
__global__ void init_out_kernel(float4* __restrict__ out4,
                                const float* __restrict__ bias,
                                int n4) {
    int i = blockIdx.x * blockDim.x + threadIdx.x;
    if (i < n4) {
        int d = (i & 3) * 4;   // DIM=16 -> 4 float4 per row
        out4[i] = make_float4(bias[d], bias[d + 1], bias[d + 2], bias[d + 3]);
    }
}

// R7 restructure: 4 lanes per weight row (lane c owns dims [4c,4c+4) as float4).
// - each gather is a dwordx4: one instruction = 16 full 64B rows per wave (was 4)
// - threads /4 (204800): 3200 waves ~ 12.5/CU, single resident scheduling round
// - 32-bit byte offsets (id<<6 < 2^26) -> saddr + voffset, no 64-bit addc chains
// Sorted segment_ids -> register run-length accumulate; atomicAdd only at
// segment boundaries (~1.3 flushes/stream, 4 scalar atomics per flush per lane;
// total lane-atomic count unchanged vs R6).
// NOTE (R5): __builtin_nontemporal_load on the gathers REGRESSED (+6us) --
// the ~1.46x row reuse needs L2 capture. Keep plain loads.
__global__ __launch_bounds__(256) void features_linear_kernel(
    const int*   __restrict__ ids,
    const float* __restrict__ ratings,
    const int*   __restrict__ segs,
    const float* __restrict__ weight,
    float*       __restrict__ out,
    int total) {
    int tid = blockIdx.x * blockDim.x + threadIdx.x;
    int c4 = (tid & 3) << 2;        // float offset of this lane's quad in a row
    int stream_id = tid >> 2;
    int t0 = stream_id * K_TOK;
    if (t0 >= total) return;

    const char* wb = (const char*)weight;
    unsigned cb = (unsigned)c4 << 2;   // byte offset within row: 0/16/32/48

    float4 acc = make_float4(0.f, 0.f, 0.f, 0.f);
    int prev = segs[t0];

#define FLUSH()                                                            \
    do {                                                                   \
        float* o = out + (((unsigned)prev) << 4) + c4;                     \
        atomicAdd(o + 0, acc.x); atomicAdd(o + 1, acc.y);                  \
        atomicAdd(o + 2, acc.z); atomicAdd(o + 3, acc.w);                  \
        acc = make_float4(0.f, 0.f, 0.f, 0.f);                             \
    } while (0)

#define GATHER(idx) (*(const float4*)(wb + (((unsigned)(idx)) << 6) + cb))

    if (t0 + K_TOK <= total) {
        const int4*   idv = (const int4*)(ids + t0);
        const float4* rv  = (const float4*)(ratings + t0);
        const int4*   sv  = (const int4*)(segs + t0);

        int4   id0 = idv[0], id1 = idv[1], id2 = idv[2], id3 = idv[3];
        float4 r0  = rv[0],  r1  = rv[1],  r2  = rv[2],  r3  = rv[3];
        int4   s0  = sv[0],  s1  = sv[1],  s2  = sv[2],  s3  = sv[3];

        // issue all 16 row-gathers before any use: 16 dwordx4 in flight/lane
        float4 w0  = GATHER(id0.x), w1  = GATHER(id0.y),
               w2  = GATHER(id0.z), w3  = GATHER(id0.w),
               w4  = GATHER(id1.x), w5  = GATHER(id1.y),
               w6  = GATHER(id1.z), w7  = GATHER(id1.w),
               w8  = GATHER(id2.x), w9  = GATHER(id2.y),
               w10 = GATHER(id2.z), w11 = GATHER(id2.w),
               w12 = GATHER(id3.x), w13 = GATHER(id3.y),
               w14 = GATHER(id3.z), w15 = GATHER(id3.w);

#define STEP(sv_, wv_, rr_)                                                \
        if ((sv_) != prev) { FLUSH(); prev = (sv_); }                      \
        acc.x = fmaf((wv_).x, (rr_), acc.x);                               \
        acc.y = fmaf((wv_).y, (rr_), acc.y);                               \
        acc.z = fmaf((wv_).z, (rr_), acc.z);                               \
        acc.w = fmaf((wv_).w, (rr_), acc.w);

        STEP(s0.x, w0,  r0.x)  STEP(s0.y, w1,  r0.y)
        STEP(s0.z, w2,  r0.z)  STEP(s0.w, w3,  r0.w)
        STEP(s1.x, w4,  r1.x)  STEP(s1.y, w5,  r1.y)
        STEP(s1.z, w6,  r1.z)  STEP(s1.w, w7,  r1.w)
        STEP(s2.x, w8,  r2.x)  STEP(s2.y, w9,  r2.y)
        STEP(s2.z, w10, r2.z)  STEP(s2.w, w11, r2.w)
        STEP(s3.x, w12, r3.x)  STEP(s3.y, w13, r3.y)
        STEP(s3.z, w14, r3.z)  STEP(s3.w, w15, r3.w)
#undef STEP
    } else {
        for (int t = t0; t < total; ++t) {
            int seg = segs[t];
            if (seg != prev) { FLUSH(); prev = seg; }
            float4 w = GATHER(ids[t]);
            float  r = ratings[t];
            acc.x = fmaf(w.x, r, acc.x);
            acc.y = fmaf(w.y, r, acc.y);
            acc.z = fmaf(w.z, r, acc.z);
            acc.w = fmaf(w.w, r, acc.w);
        }
    }
    FLUSH();
#undef FLUSH
#undef GATHER
}

extern "C" void kernel_launch(void* const* d_in, const int* in_sizes, int n_in,
                              void* d_out, int out_size, void* d_ws, size_t ws_size,
                              hipStream_t stream) {
    const int*   ids     = (const int*)d_in[0];
    const float* ratings = (const float*)d_in[1];
    const int*   segs    = (const int*)d_in[2];
    // d_in[3] = batch_size scalar (unused; batch = out_size / DIM)
    const float* weight  = (const float*)d_in[4];
    const float* bias    = (const float*)d_in[5];
    float* out = (float*)d_out;

    int total = in_sizes[0];

    // 1) initialize output with bias (vectorized)
    {
        int n4 = out_size / 4;
        int threads = 256;
        int blocks = (n4 + threads - 1) / threads;
        init_out_kernel<<<blocks, threads, 0, stream>>>((float4*)out, bias, n4);
    }

    // 2) gather + segmented sum: 4 lanes per stream (one float4 per lane)
    {
        int n_streams = (total + K_TOK - 1) / K_TOK;
        long long n_threads = (long long)n_streams * 4;
        int threads = 256;
        int blocks = (int)((n_threads + threads - 1) / threads);
        features_linear_kernel<<<blocks, threads, 0, stream>>>(
            ids, ratings, segs, weight, out, total);
    }
}

// Round 2
// 119.669 us; speedup vs baseline: 1.0172x; 1.0172x over previous
//
#include <hip/hip_runtime.h>

#define DIM 16

// R8: segment-owned decomposition — ZERO atomics.
// segment_ids sorted => row b owns contiguous token range
// [lower_bound(b), lower_bound(b+1)). One 16-lane group per segment
// (lane = dim). 16384 groups = 4096 waves = 16/CU, all resident.
// - dual interleaved branchless binary search (~20 probes each, independent
//   dep-chains overlap; top tree levels are chip-wide shared -> L1-hot)
// - inner loop: 16-token chunks: 16 broadcast id/rating loads, 16 coalesced
//   64B row-gathers (16 lanes x dword = one line), 16 FMAs. Tail handled by
//   clamped addresses + zeroed rating (group-uniform predicates, no branches).
// - epilogue: ONE plain coalesced store of acc + bias[d]. init kernel deleted
//   (every row written exactly once; empty segment -> bias).
// NOTE (R5): __builtin_nontemporal_load on gathers REGRESSED (+6us) -- the
// ~1.46x row reuse needs L2 capture. Keep plain loads.
// NOTE (R7): 4-lane/dwordx4 gathers (4x fewer VMEM instr) REGRESSED (+5us);
// kernel is not VMEM-issue-bound. Flush/atomic path was the suspect cost;
// this version removes it entirely.
__global__ __launch_bounds__(256) void features_linear_seg_kernel(
    const int*   __restrict__ ids,
    const float* __restrict__ ratings,
    const int*   __restrict__ segs,
    const float* __restrict__ weight,
    const float* __restrict__ bias,
    float*       __restrict__ out,
    int total,
    int batch) {
    int tid = blockIdx.x * blockDim.x + threadIdx.x;
    int d = tid & (DIM - 1);
    int b = tid >> 4;             // segment id; one 16-lane group per segment
    if (b >= batch) return;

    // --- dual branchless lower_bound: lo0 = first t with segs[t] >= b,
    //     lo1 = first t with segs[t] >  b  (== lower_bound(b+1), sorted)
    int lo0 = 0, n0 = total;
    int lo1 = 0, n1 = total;
    int last = total - 1;
    while ((n0 | n1) != 0) {
        int h0 = n0 >> 1; int m0 = lo0 + h0; m0 = m0 < last ? m0 : last;
        int h1 = n1 >> 1; int m1 = lo1 + h1; m1 = m1 < last ? m1 : last;
        int v0 = segs[m0];                 // two independent loads per iter
        int v1 = segs[m1];
        bool p0 = (n0 > 0) & (v0 < b);
        bool p1 = (n1 > 0) & (v1 <= b);
        lo0 = p0 ? m0 + 1 : lo0;
        lo1 = p1 ? m1 + 1 : lo1;
        n0  = p0 ? (n0 - h0 - 1) : h0;     // n==0 -> h==0 -> stays 0
        n1  = p1 ? (n1 - h1 - 1) : h1;
    }

    // --- accumulate this segment's tokens, 16 per chunk
    const char* wb = (const char*)weight;
    unsigned db = (unsigned)d << 2;        // byte offset of dim d within a row
    float acc = 0.0f;

    int lastt = lo1 - 1;                   // valid iff segment non-empty
    for (int base = lo0; base < lo1; base += 16) {
        int   idv[16];
        float rv[16];
        #pragma unroll
        for (int i = 0; i < 16; ++i) {
            int t  = base + i;
            int tc = t < lastt ? t : lastt;    // clamp -> loads always safe
            idv[i] = ids[tc];
            float r = ratings[tc];
            rv[i]  = (t <= lastt) ? r : 0.0f;  // mask tail via rating = 0
        }
        float wv[16];
        #pragma unroll
        for (int i = 0; i < 16; ++i)
            wv[i] = *(const float*)(wb + (((unsigned)idv[i]) << 6) + db);
        #pragma unroll
        for (int i = 0; i < 16; ++i)
            acc = fmaf(wv[i], rv[i], acc);
    }

    // --- exclusive owner: plain coalesced store (64B per group)
    out[(((unsigned)b) << 4) + d] = acc + bias[d];
}

extern "C" void kernel_launch(void* const* d_in, const int* in_sizes, int n_in,
                              void* d_out, int out_size, void* d_ws, size_t ws_size,
                              hipStream_t stream) {
    const int*   ids     = (const int*)d_in[0];
    const float* ratings = (const float*)d_in[1];
    const int*   segs    = (const int*)d_in[2];
    // d_in[3] = batch_size scalar (unused; batch = out_size / DIM)
    const float* weight  = (const float*)d_in[4];
    const float* bias    = (const float*)d_in[5];
    float* out = (float*)d_out;

    int total = in_sizes[0];
    int batch = out_size / DIM;   // out_size counts floats

    long long n_threads = (long long)batch * DIM;
    int threads = 256;
    int blocks = (int)((n_threads + threads - 1) / threads);
    features_linear_seg_kernel<<<blocks, threads, 0, stream>>>(
        ids, ratings, segs, weight, bias, out, total, batch);
}

// Round 3
// 113.974 us; speedup vs baseline: 1.0680x; 1.0500x over previous
//
#include <hip/hip_runtime.h>

#define DIM 16
#define TOK_PB 256   // tokens per block == threads per block (16 groups x 16 tokens)

// out[b*DIM + d] = bias[d], vectorized float4 (d_out poisoned pre-launch)
__global__ void init_out_kernel(float4* __restrict__ out4,
                                const float* __restrict__ bias,
                                int n4) {
    int i = blockIdx.x * blockDim.x + threadIdx.x;
    if (i < n4) {
        int d = (i & 3) * 4;   // DIM=16 -> 4 float4 per row
        out4[i] = make_float4(bias[d], bias[d + 1], bias[d + 2], bias[d + 3]);
    }
}

// R9: LDS-staged token data; VGPR pool spent on gather destinations only.
// Evidence trail:
//  R6 (16-lane streams, regs for token data): best, ~16 waves/CU x 64
//     lines-in-flight/wave ~ 1024 outstanding lines/CU.
//  R7 (dwordx4 gathers, 4x fewer VMEM instr): +5us -> not VMEM-issue-bound.
//  R8 (zero atomics, binary search): +3us -> not atomic-bound.
//  => kernel is MLP/miss-queue bound on random 64B row gathers (L3 scrubbed
//     by harness 256MiB fills each iter => cold HBM random fetch ~46MB).
// This version: block stages its 256 tokens' (id,rating,seg) into 3KB LDS
// (coalesced write, 2-way-free banks; group-uniform ds_read = broadcast).
// Per-thread state ~ 16 w-dests + transient ids -> fits 64 VGPR ->
// __launch_bounds__(256,8) gives 8 waves/SIMD: ~512 lines/SIMD, 2x R6.
// Flush scheme identical to R6: sorted segs -> register run-length, atomic
// only at segment boundaries.
// NOTE (R5): __builtin_nontemporal_load on gathers REGRESSED (+6us). Keep
// plain loads (intra-iteration L2 reuse ~1.46x).
__global__ __launch_bounds__(256, 8) void features_linear_kernel(
    const int*   __restrict__ ids,
    const float* __restrict__ ratings,
    const int*   __restrict__ segs,
    const float* __restrict__ weight,
    float*       __restrict__ out,
    int total) {
    __shared__ int   sh_id[TOK_PB];
    __shared__ float sh_r [TOK_PB];
    __shared__ int   sh_s [TOK_PB];

    int j    = threadIdx.x;
    int t0b  = blockIdx.x * TOK_PB;
    int nrem = total - t0b;                 // >= 1 by grid construction
    int jc   = j < nrem ? j : nrem - 1;     // clamp -> staging loads always safe
    int tj   = t0b + jc;
    sh_id[j] = ids[tj];
    sh_r [j] = ratings[tj];
    sh_s [j] = segs[tj];
    __syncthreads();

    int d    = j & (DIM - 1);
    int g    = j >> 4;                      // group id: one 16-token stream
    int base = g << 4;                      // group's first token in LDS
    if (base >= nrem) return;               // after barrier: legal early-exit

    const char* wb = (const char*)weight;
    unsigned db = (unsigned)d << 2;         // byte offset of dim d in a row
    float acc = 0.0f;
    int prev = sh_s[base];

    if (base + 16 <= nrem) {
        // issue all 16 row-gathers before any use: 16 lines/group in flight
        int idv[16];
        #pragma unroll
        for (int i = 0; i < 16; ++i) idv[i] = sh_id[base + i];
        float w[16];
        #pragma unroll
        for (int i = 0; i < 16; ++i)
            w[i] = *(const float*)(wb + (((unsigned)idv[i]) << 6) + db);

        #pragma unroll
        for (int i = 0; i < 16; ++i) {
            int   seg = sh_s[base + i];     // uniform ds_read: broadcast
            float r   = sh_r[base + i];
            if (seg != prev) {
                atomicAdd(&out[prev * DIM + d], acc);
                acc = 0.0f; prev = seg;
            }
            acc = fmaf(w[i], r, acc);
        }
    } else {
        // partial group in the last block
        for (int i = base; i < nrem; ++i) {
            int seg = sh_s[i];
            if (seg != prev) {
                atomicAdd(&out[prev * DIM + d], acc);
                acc = 0.0f; prev = seg;
            }
            float w = *(const float*)(wb + (((unsigned)sh_id[i]) << 6) + db);
            acc = fmaf(w, sh_r[i], acc);
        }
    }
    atomicAdd(&out[prev * DIM + d], acc);
}

extern "C" void kernel_launch(void* const* d_in, const int* in_sizes, int n_in,
                              void* d_out, int out_size, void* d_ws, size_t ws_size,
                              hipStream_t stream) {
    const int*   ids     = (const int*)d_in[0];
    const float* ratings = (const float*)d_in[1];
    const int*   segs    = (const int*)d_in[2];
    // d_in[3] = batch_size scalar (unused; batch = out_size / DIM)
    const float* weight  = (const float*)d_in[4];
    const float* bias    = (const float*)d_in[5];
    float* out = (float*)d_out;

    int total = in_sizes[0];

    // 1) initialize output with bias (vectorized)
    {
        int n4 = out_size / 4;
        int threads = 256;
        int blocks = (n4 + threads - 1) / threads;
        init_out_kernel<<<blocks, threads, 0, stream>>>((float4*)out, bias, n4);
    }

    // 2) gather + segmented sum, LDS-staged token data
    {
        int blocks = (total + TOK_PB - 1) / TOK_PB;
        features_linear_kernel<<<blocks, TOK_PB, 0, stream>>>(
            ids, ratings, segs, weight, out, total);
    }
}

// Round 6
// 113.047 us; speedup vs baseline: 1.0768x; 1.0082x over previous
//
#include <hip/hip_runtime.h>

#define DIM 16
#define K_TOK 32                 // tokens per 16-lane group
#define GROUPS 16                // groups per 256-thread block
#define TOK_PB (GROUPS * K_TOK)  // 512 tokens staged per block

// out[b*DIM + d] = bias[d], vectorized float4 (d_out poisoned pre-launch)
__global__ void init_out_kernel(float4* __restrict__ out4,
                                const float* __restrict__ bias,
                                int n4) {
    int i = blockIdx.x * blockDim.x + threadIdx.x;
    if (i < n4) {
        int d = (i & 3) * 4;   // DIM=16 -> 4 float4 per row
        out4[i] = make_float4(bias[d], bias[d + 1], bias[d + 2], bias[d + 3]);
    }
}

// R10 (2nd rerun; R4+R5 benches were infra failures — container acquisition
// failed before any compile/test, same submission ran clean as R9 structure):
// R9 LDS-staged structure, K_TOK 16 -> 32.
// Evidence trail:
//  R6 regs-for-tokens baseline ~116.5; R7 dwordx4/4-lane +5 (not VMEM-issue
//  bound); R8 zero-atomic binary search +3 (search = ~20 serial probes ~7.5us,
//  so atomics ~= 3us); R9 LDS staging + 8 waves/SIMD -2.5 (2x nominal MLP ->
//  only ~8% of kernel portion: per-CU miss queue saturated, Q_eff ~ 43).
// => gather is at its miss-queue latency floor for 3200 lines/CU; remaining
//    slack is atomic issue (~3us) + per-stream overhead. K_TOK=32 halves
//    final-flush atomics (819k -> 410k; boundary flushes 262k fixed) and
//    halves stream prologue/epilogue, with the gather loop unchanged.
// NOTE (R5): __builtin_nontemporal_load on gathers REGRESSED (+6us). Keep
// plain loads (weight reuse ~1.46x needs L2/L3 capture).
__global__ __launch_bounds__(256, 8) void features_linear_kernel(
    const int*   __restrict__ ids,
    const float* __restrict__ ratings,
    const int*   __restrict__ segs,
    const float* __restrict__ weight,
    float*       __restrict__ out,
    int total) {
    __shared__ int   sh_id[TOK_PB];
    __shared__ float sh_r [TOK_PB];
    __shared__ int   sh_s [TOK_PB];

    int j    = threadIdx.x;
    int t0b  = blockIdx.x * TOK_PB;
    int nrem = total - t0b;                  // >= 1 by grid construction
    #pragma unroll
    for (int k = 0; k < TOK_PB / 256; ++k) {
        int idx = j + k * 256;
        int ic  = idx < nrem ? idx : nrem - 1;   // clamp -> loads always safe
        int t   = t0b + ic;
        sh_id[idx] = ids[t];
        sh_r [idx] = ratings[t];
        sh_s [idx] = segs[t];
    }
    __syncthreads();

    int d    = j & (DIM - 1);
    int g    = j >> 4;                       // group id: one K_TOK-token stream
    int base = g * K_TOK;                    // group's first token in LDS
    if (base >= nrem) return;                // after barrier: legal early-exit

    const char* wb = (const char*)weight;
    unsigned db = (unsigned)d << 2;          // byte offset of dim d in a row
    float acc = 0.0f;
    int prev = sh_s[base];

    if (base + K_TOK <= nrem) {
        // issue the row-gathers ahead of use; launch_bounds caps VGPR at 64,
        // compiler batches the 32 loads to fit (>= R9 depth at any instant)
        float w[K_TOK];
        #pragma unroll
        for (int i = 0; i < K_TOK; ++i)
            w[i] = *(const float*)(wb + (((unsigned)sh_id[base + i]) << 6) + db);

        #pragma unroll
        for (int i = 0; i < K_TOK; ++i) {
            int   seg = sh_s[base + i];      // uniform ds_read: broadcast
            float r   = sh_r[base + i];
            if (seg != prev) {
                atomicAdd(&out[prev * DIM + d], acc);
                acc = 0.0f; prev = seg;
            }
            acc = fmaf(w[i], r, acc);
        }
    } else {
        // partial group in the last block
        for (int i = base; i < nrem; ++i) {
            int seg = sh_s[i];
            if (seg != prev) {
                atomicAdd(&out[prev * DIM + d], acc);
                acc = 0.0f; prev = seg;
            }
            float w = *(const float*)(wb + (((unsigned)sh_id[i]) << 6) + db);
            acc = fmaf(w, sh_r[i], acc);
        }
    }
    atomicAdd(&out[prev * DIM + d], acc);
}

extern "C" void kernel_launch(void* const* d_in, const int* in_sizes, int n_in,
                              void* d_out, int out_size, void* d_ws, size_t ws_size,
                              hipStream_t stream) {
    const int*   ids     = (const int*)d_in[0];
    const float* ratings = (const float*)d_in[1];
    const int*   segs    = (const int*)d_in[2];
    // d_in[3] = batch_size scalar (unused; batch = out_size / DIM)
    const float* weight  = (const float*)d_in[4];
    const float* bias    = (const float*)d_in[5];
    float* out = (float*)d_out;

    int total = in_sizes[0];

    // 1) initialize output with bias (vectorized)
    {
        int n4 = out_size / 4;
        int threads = 256;
        int blocks = (n4 + threads - 1) / threads;
        init_out_kernel<<<blocks, threads, 0, stream>>>((float4*)out, bias, n4);
    }

    // 2) gather + segmented sum, LDS-staged token data, 32 tokens/group
    {
        int blocks = (total + TOK_PB - 1) / TOK_PB;
        features_linear_kernel<<<blocks, 256, 0, stream>>>(
            ids, ratings, segs, weight, out, total);
    }
}